// Round 1
// baseline (461.229 us; speedup 1.0000x reference)
//
#include <hip/hip_runtime.h>
#include <hip/hip_bf16.h>

// ---------------------------------------------------------------------------
// DynamicTransformer, round 5 = round 4 + cc-loop live-set reduction.
//
// Round-4 diagnosis: FETCH_SIZE=433MB vs ~48MB compulsory, WRITE=192MB vs
// 75.5MB ideal, VGPR_Count==128 exactly (arch cap), MfmaUtil 6% -> the cc
// loop STILL spills ~16-20 arch regs (live set ~144 vs 128 arch split);
// ~1.3KB/thread of scratch fills = the 380MB FETCH excess, and every fill
// is a ~900-cyc HBM stall at only 2 waves/SIMD.
//
// Fix: replace the 3x3 f32x4 h-window (36 regs) with 3 rotating conv
// partial-sum accumulators yacc[3] (12 regs). Each h row produced at rr
// contributes tap-row dy=rr-py to outputs py in {rr-2,rr-1,rr}; an output
// is emitted (LeakyReLU -> bf16 -> 4 proj_out MFMAs) when dy==2. Same
// FLOPs, same tap pairing, -24 arch regs -> peak arch ~120 <= 128.
// All py/slot indices are compile-time after full unroll.
//
//  prepw : w_in / w_out -> bf16 in exact MFMA fragment order (global)
//  prepx : x (b,c,y,x) f32 -> xT (b, y+1, x+1, c) bf16 with zero border,
//          fused per-(b,c) channel sums (for the kernel generator)
//  kgen  : exact-fp32 dynamic kernel generator -> karr[b][tap][o]
//  kmain : 16x16 aligned output tiles; h lives in f32 registers between
//          proj_in MFMA and the depthwise conv; one barrier for compute;
//          stores bounce through LDS for aligned 64B f32x4 rows.
// ---------------------------------------------------------------------------

typedef __bf16 bf16;
typedef __bf16 bf16x4 __attribute__((ext_vector_type(4)));
typedef __bf16 bf16x8 __attribute__((ext_vector_type(8)));
typedef float  f32x4  __attribute__((ext_vector_type(4)));

#define B_   8
#define DIM_ 64
#define HID_ 128
#define HW_  192
#define PW_  194            // padded width/height of xT

__device__ __forceinline__ void gl_lds16(const void* g, void* l) {
  __builtin_amdgcn_global_load_lds((__attribute__((address_space(1))) void*)(g),
                                   (__attribute__((address_space(3))) void*)(l),
                                   16, 0, 0);
}

// ws layout (bytes)
#define WS_XT    0u            // 8*194*194*64*2 = 38,539,264
#define WS_XSUM  38539264u     // 512 f32
#define WS_KARR  38541312u     // 8 * 9*128 f32 = 36,864
#define WS_WIA   38578176u     // 8192 bf16 = 16,384
#define WS_WOB   38594560u     // 16384 bf16 = 32,768

// ---------------------------------------------------------------------------
// prepw: w_in -> A-frag order [cc][kk][q][m][j] (o=16cc+m, c=32kk+8q+j)
//        w_out -> B-frag order [cc][q][j64][slot8] (slot<4: w_out[j][16cc+4q+slot], else 0)
// 24576 threads: 8192 for wiA, 16384 for woB.
// ---------------------------------------------------------------------------
__global__ __launch_bounds__(256) void dt_prepw(const float* __restrict__ w_in,
                                                const float* __restrict__ w_out,
                                                bf16* __restrict__ wiA,
                                                bf16* __restrict__ woB) {
  int i = blockIdx.x * 256 + threadIdx.x;          // 0..24575
  if (i < 8192) {
    int j = i & 7, m = (i >> 3) & 15, q = (i >> 7) & 3, kk = (i >> 9) & 1, cc = i >> 10;
    int o = cc * 16 + m, c = kk * 32 + q * 8 + j;
    wiA[i] = (bf16)w_in[o * DIM_ + c];
  } else {
    int i2 = i - 8192;                             // 0..16383
    int sl = i2 & 7, j = (i2 >> 3) & 63, q = (i2 >> 9) & 3, cc = i2 >> 11;  // cc 0..7
    float v = (sl < 4) ? w_out[j * HID_ + cc * 16 + q * 4 + sl] : 0.f;
    woB[i2] = (bf16)v;
  }
}

// ---------------------------------------------------------------------------
// prepx: one block per (b, padded row yy). Interior rows: transpose 64x192
// f32 -> 192 px * 64c bf16 (via LDS), plus channel partial sums -> atomicAdd.
// Border rows / cols written as zeros.
// ---------------------------------------------------------------------------
__global__ __launch_bounds__(256) void dt_prepx(const float* __restrict__ x,
                                                bf16* __restrict__ xT,
                                                float* __restrict__ xsum) {
  const int yy = blockIdx.x, b = blockIdx.y, t = threadIdx.x;
  bf16* xtrow = xT + ((size_t)(b * PW_ + yy)) * PW_ * DIM_;
  const bf16x8 z8 = {(bf16)0.f,(bf16)0.f,(bf16)0.f,(bf16)0.f,
                     (bf16)0.f,(bf16)0.f,(bf16)0.f,(bf16)0.f};
  if (yy == 0 || yy == PW_ - 1) {
    if (t < PW_) {
      bf16* dst = xtrow + t * DIM_;
#pragma unroll
      for (int c8 = 0; c8 < 8; ++c8) *(bf16x8*)(dst + c8 * 8) = z8;
    }
    return;
  }
  const int y = yy - 1;
  __shared__ float xr[DIM_ * HW_];                 // [c][px]
  const int c = t >> 2, qu = t & 3;
  const float4* rp = (const float4*)(x + ((size_t)(b * DIM_ + c) * HW_ + y) * HW_) + qu * 12;
  float s = 0.f;
#pragma unroll
  for (int i = 0; i < 12; ++i) {
    float4 v = rp[i];
    s += (v.x + v.y) + (v.z + v.w);
    ((float4*)xr)[c * 48 + qu * 12 + i] = v;
  }
  s += __shfl_down(s, 2);
  s += __shfl_down(s, 1);
  if ((t & 3) == 0) atomicAdd(xsum + b * DIM_ + c, s);
  __syncthreads();
  if (t < HW_) {
    const int px = t;
    bf16* dst = xtrow + (px + 1) * DIM_;
#pragma unroll
    for (int c8 = 0; c8 < 8; ++c8) {
      bf16x8 pk;
#pragma unroll
      for (int j2 = 0; j2 < 8; ++j2) pk[j2] = (bf16)xr[(c8 * 8 + j2) * HW_ + px];
      *(bf16x8*)(dst + c8 * 8) = pk;
    }
  } else if (t == HW_ || t == HW_ + 1) {           // border cols xx=0, xx=193
    bf16* dst = xtrow + (size_t)(t - HW_) * (PW_ - 1) * DIM_;
#pragma unroll
    for (int c8 = 0; c8 < 8; ++c8) *(bf16x8*)(dst + c8 * 8) = z8;
  }
}

// ---------------------------------------------------------------------------
// kgen: exact fp32. karr[b][tap][o], tap-major so kmain reads f32x4 over o.
// ---------------------------------------------------------------------------
__global__ __launch_bounds__(128) void dt_kgen(
    const float* __restrict__ xsum, const float* __restrict__ w_in,
    const float* __restrict__ b_in, const float* __restrict__ wg1,
    const float* __restrict__ bg1, const float* __restrict__ wg2,
    const float* __restrict__ bg2, float* __restrict__ karr) {
  const int b = blockIdx.x, t = threadIdx.x;
  __shared__ float xm[DIM_], hm[HID_], g[HID_];
  if (t < DIM_) xm[t] = xsum[b * DIM_ + t] * (1.f / (HW_ * HW_));
  __syncthreads();
  {
    float a = b_in[t];
    const float* w = w_in + t * DIM_;
    for (int c = 0; c < DIM_; ++c) a += w[c] * xm[c];
    hm[t] = a;
  }
  __syncthreads();
  {
    float a = bg1[t];
    const float* w = wg1 + t * HID_;
    for (int c = 0; c < HID_; ++c) a += w[c] * hm[c];
    g[t] = a > 0.f ? a : 0.f;
  }
  __syncthreads();
  for (int tp = 0; tp < 9; ++tp) {
    float s = bg2[t * 9 + tp];
    const float* w2 = wg2 + (size_t)(t * 9 + tp) * HID_;
    for (int c = 0; c < HID_; ++c) s += w2[c] * g[c];
    karr[b * 1152 + tp * HID_ + t] = s;
  }
}

// ---------------------------------------------------------------------------
// kmain. Grid (12,12,8), 256 threads (4 waves). Wave wv owns out rows
// 4wv..4wv+3 of the tile (h tile rows 4wv..4wv+5).
// LDS: [0,41472) x_s: 18 rows x (kk2 x q4 x px18) 16B chunks
//      [41472,46080) karr f32 [tap][128]
//      store bounce aliases [0,34048) after compute barrier.
// __launch_bounds__(256,2): 256-VGPR unified budget (2 blocks/CU). Peak
// arch live set ~120 (kv 36 + yacc 12 + wa 8 + wb 16 + bin 4 + x/h
// transients + addr) + acc3 64 in AGPR -> must be NO scratch spill.
// ---------------------------------------------------------------------------
#define XROWB 2304
#define KOFF  41472

__global__ __launch_bounds__(256, 2) void dt_kmain(
    const bf16* __restrict__ xT, const bf16* __restrict__ wiA,
    const bf16* __restrict__ woB, const float* __restrict__ karr,
    const float* __restrict__ b_in, const float* __restrict__ b_out,
    float* __restrict__ out) {
  __shared__ __attribute__((aligned(16))) char smem[46080];
  const int t = threadIdx.x;
  const int wv = t >> 6, lane = t & 63;
  const int q = lane >> 4, m = lane & 15;
  const int tx = blockIdx.x, ty = blockIdx.y, b = blockIdx.z;

  // ---- stage x tile + karr via global_load_lds ---------------------------
  {
    const char* xbase = (const char*)xT +
        ((size_t)(b * PW_ + ty * 16) * PW_ + tx * 16) * (DIM_ * 2);
    for (int rr = wv; rr < 18; rr += 4) {
      const char* grow = xbase + (size_t)rr * (PW_ * DIM_ * 2);
      char* lrow = smem + rr * XROWB;
#pragma unroll
      for (int p = 0; p < 3; ++p) {
        int idx = p * 64 + lane;
        if (idx < 144) {
          int kq = (idx * 57) >> 10;        // idx / 18
          int px = idx - kq * 18;
          int goff = px * 128 + (kq >> 2) * 64 + (kq & 3) * 16;
          gl_lds16(grow + goff, lrow + p * 1024);
        }
      }
    }
    const char* kg = (const char*)karr + b * 4608;
    gl_lds16(kg + (wv * 64 + lane) * 16, smem + KOFF + wv * 1024);
    if (wv == 0 && lane < 32)
      gl_lds16(kg + (256 + lane) * 16, smem + KOFF + 4096);
  }
  __syncthreads();

  const int rowg0 = ty * 16 - 1;
  const int colg0 = tx * 16 - 1;
  const float mL = ((unsigned)(colg0 + 0 + m) < (unsigned)HW_) ? 1.f : 0.f;
  const float mM = ((unsigned)(colg0 + 1 + m) < (unsigned)HW_) ? 1.f : 0.f;
  const float mR = ((unsigned)(colg0 + 2 + m) < (unsigned)HW_) ? 1.f : 0.f;

  f32x4 acc3[4][4];
#pragma unroll
  for (int a = 0; a < 4; ++a)
#pragma unroll
    for (int n = 0; n < 4; ++n) acc3[a][n] = 0.f;

  const float* karrL = (const float*)(smem + KOFF);

  for (int cc = 0; cc < 8; ++cc) {
    const bf16x8 wa0 = *(const bf16x8*)((const char*)wiA + ((cc * 2 + 0) * 4 + q) * 256 + m * 16);
    const bf16x8 wa1 = *(const bf16x8*)((const char*)wiA + ((cc * 2 + 1) * 4 + q) * 256 + m * 16);
    // proj_out B-frags: py-invariant -> hoisted once per cc
    const bf16x8 wb0 = *(const bf16x8*)((const char*)woB + (((cc * 4 + q) * 64) + 0 * 16 + m) * 16);
    const bf16x8 wb1 = *(const bf16x8*)((const char*)woB + (((cc * 4 + q) * 64) + 1 * 16 + m) * 16);
    const bf16x8 wb2 = *(const bf16x8*)((const char*)woB + (((cc * 4 + q) * 64) + 2 * 16 + m) * 16);
    const bf16x8 wb3 = *(const bf16x8*)((const char*)woB + (((cc * 4 + q) * 64) + 3 * 16 + m) * 16);
    const f32x4 bin4 = *(const f32x4*)(b_in + cc * 16 + q * 4);
    f32x4 kv[9];
#pragma unroll
    for (int tp = 0; tp < 9; ++tp)
      kv[tp] = *(const f32x4*)(karrL + tp * HID_ + cc * 16 + q * 4);

    // Rotating conv partial sums: slot py%3 accumulates output row py while
    // its 3-row h window streams past. Replaces the 36-reg hwin window.
    f32x4 yacc[3];
#pragma unroll
    for (int rr = 0; rr < 6; ++rr) {
      const int row = wv * 4 + rr;
      const char* rbase = smem + row * XROWB + q * 288 + m * 16;
      f32x4 z = 0.f;
      bf16x8 x0L = *(const bf16x8*)(rbase);
      bf16x8 x1L = *(const bf16x8*)(rbase + 1152);
      f32x4 hL = __builtin_amdgcn_mfma_f32_16x16x32_bf16(wa0, x0L, z, 0, 0, 0);
      hL = __builtin_amdgcn_mfma_f32_16x16x32_bf16(wa1, x1L, hL, 0, 0, 0);
      bf16x8 x0M = *(const bf16x8*)(rbase + 16);
      bf16x8 x1M = *(const bf16x8*)(rbase + 1152 + 16);
      f32x4 hM = __builtin_amdgcn_mfma_f32_16x16x32_bf16(wa0, x0M, z, 0, 0, 0);
      hM = __builtin_amdgcn_mfma_f32_16x16x32_bf16(wa1, x1M, hM, 0, 0, 0);
      bf16x8 x0R = *(const bf16x8*)(rbase + 32);
      bf16x8 x1R = *(const bf16x8*)(rbase + 1152 + 32);
      f32x4 hR = __builtin_amdgcn_mfma_f32_16x16x32_bf16(wa0, x0R, z, 0, 0, 0);
      hR = __builtin_amdgcn_mfma_f32_16x16x32_bf16(wa1, x1R, hR, 0, 0, 0);
      if ((unsigned)(rowg0 + row) < (unsigned)HW_) {   // wave-uniform
        hL += bin4 * mL;
        hM += bin4 * mM;
        hR += bin4 * mR;
      }
      // h row rr is tap-row dy = rr-py for in-flight outputs py.
#pragma unroll
      for (int py = (rr >= 2 ? rr - 2 : 0); py <= (rr <= 3 ? rr : 3); ++py) {
        const int dy = rr - py;
        const int s = py % 3;                 // compile-time after unroll
        if (dy == 0) {
          yacc[s] = kv[0] * hL + kv[1] * hM + kv[2] * hR;
        } else if (dy == 1) {
          yacc[s] += kv[3] * hL;
          yacc[s] += kv[4] * hM;
          yacc[s] += kv[5] * hR;
        } else {
          f32x4 v = yacc[s] + kv[6] * hL + kv[7] * hM + kv[8] * hR;
          bf16 yf[4];
#pragma unroll
          for (int r = 0; r < 4; ++r) {
            float vv = v[r];
            vv = fmaxf(vv, 0.1f * vv);                 // LeakyReLU(0.1)
            yf[r] = (bf16)vv;
          }
          bf16x8 af = {yf[0], yf[1], yf[2], yf[3],
                       (bf16)0.f, (bf16)0.f, (bf16)0.f, (bf16)0.f};
          acc3[py][0] = __builtin_amdgcn_mfma_f32_16x16x32_bf16(af, wb0, acc3[py][0], 0, 0, 0);
          acc3[py][1] = __builtin_amdgcn_mfma_f32_16x16x32_bf16(af, wb1, acc3[py][1], 0, 0, 0);
          acc3[py][2] = __builtin_amdgcn_mfma_f32_16x16x32_bf16(af, wb2, acc3[py][2], 0, 0, 0);
          acc3[py][3] = __builtin_amdgcn_mfma_f32_16x16x32_bf16(af, wb3, acc3[py][3], 0, 0, 0);
        }
      }
    }
  }
  __syncthreads();          // x_s / karr dead; bounce region reuses smem

  // ---- store via LDS bounce: aligned 64B f32x4 rows ----------------------
  float* smemF = (float*)smem;                      // [j][132] f32, halves of 8 rows
  const int c4 = t & 3, js = (t >> 2) & 63;
  const float bo = b_out[js];
  float* obase = out + ((size_t)(b * DIM_ + js) * HW_ + (ty * 16)) * HW_ + tx * 16 + c4 * 4;
#pragma unroll
  for (int half = 0; half < 2; ++half) {
    if ((wv >> 1) == half) {
#pragma unroll
      for (int py = 0; py < 4; ++py) {
        const int lrow = (wv * 4 + py) & 7;
#pragma unroll
        for (int nt = 0; nt < 4; ++nt)
          *(f32x4*)(smemF + (nt * 16 + m) * 132 + lrow * 16 + q * 4) = acc3[py][nt];
      }
    }
    __syncthreads();
#pragma unroll
    for (int lrow = 0; lrow < 8; ++lrow) {
      f32x4 v = *(const f32x4*)(smemF + js * 132 + lrow * 16 + c4 * 4);
      v += bo;
      *(f32x4*)(obase + (size_t)(half * 8 + lrow) * HW_) = v;
    }
    __syncthreads();
  }
}

// ---------------------------------------------------------------------------
extern "C" void kernel_launch(void* const* d_in, const int* in_sizes, int n_in,
                              void* d_out, int out_size, void* d_ws,
                              size_t ws_size, hipStream_t stream) {
  const float* x     = (const float*)d_in[0];
  const float* w_in  = (const float*)d_in[1];
  const float* b_in  = (const float*)d_in[2];
  const float* wg1   = (const float*)d_in[3];
  const float* bg1   = (const float*)d_in[4];
  const float* wg2   = (const float*)d_in[5];
  const float* bg2   = (const float*)d_in[6];
  const float* w_out = (const float*)d_in[7];
  const float* b_out = (const float*)d_in[8];
  float* out = (float*)d_out;

  char* ws = (char*)d_ws;
  bf16*  xT   = (bf16*)(ws + WS_XT);
  float* xsum = (float*)(ws + WS_XSUM);
  float* karr = (float*)(ws + WS_KARR);
  bf16*  wiA  = (bf16*)(ws + WS_WIA);
  bf16*  woB  = (bf16*)(ws + WS_WOB);

  hipMemsetAsync(xsum, 0, B_ * DIM_ * sizeof(float), stream);
  dt_prepw<<<dim3(96), dim3(256), 0, stream>>>(w_in, w_out, wiA, woB);
  dt_prepx<<<dim3(PW_, B_), dim3(256), 0, stream>>>(x, xT, xsum);
  dt_kgen<<<dim3(B_), dim3(128), 0, stream>>>(xsum, w_in, b_in, wg1, bg1, wg2,
                                              bg2, karr);
  dt_kmain<<<dim3(12, 12, B_), dim3(256), 0, stream>>>(xT, wiA, woB, karr,
                                                       b_in, b_out, out);
}

// Round 3
// 330.440 us; speedup vs baseline: 1.3958x; 1.3958x over previous
//
#include <hip/hip_runtime.h>
#include <hip/hip_bf16.h>

// ---------------------------------------------------------------------------
// DynamicTransformer, round 7 = round 6 resubmission (container infra failure,
// kernel never measured).
//
// Round-5 post-mortem: yacc[py%3] inside a variable-bound #pragma unroll
// loop -> unroller could not prove constant trip count -> yacc demoted to
// scratch (rule #20). WRITE_SIZE 192->528MB was the scratch-store signature.
//
// Round-6/7 fix, same intent with zero runtime indexing:
//  * hwin[3][3] (36 regs) -> named rotating conv accumulators y0..y3,
//    hand-unrolled rr=0..5; every slot and acc3[PY] index is a literal.
//  * kv[9] (36 regs) no longer held: each 3-tap group is re-read from LDS
//    (karrL) at its use site. Broadcast reads (16 lanes/address) =
//    conflict-free; ~27 extra ds_read_b128 per cc on the LDS pipe, which
//    overlaps MFMA. Peak arch live ~90 << 128 arch split -> no spill.
//
//  prepw : w_in / w_out -> bf16 in exact MFMA fragment order (global)
//  prepx : x (b,c,y,x) f32 -> xT (b, y+1, x+1, c) bf16 with zero border,
//          fused per-(b,c) channel sums (for the kernel generator)
//  kgen  : exact-fp32 dynamic kernel generator -> karr[b][tap][o]
//  kmain : 16x16 aligned output tiles; h lives in f32 registers between
//          proj_in MFMA and the depthwise conv; one barrier for compute;
//          stores bounce through LDS for aligned 64B f32x4 rows.
// ---------------------------------------------------------------------------

typedef __bf16 bf16;
typedef __bf16 bf16x4 __attribute__((ext_vector_type(4)));
typedef __bf16 bf16x8 __attribute__((ext_vector_type(8)));
typedef float  f32x4  __attribute__((ext_vector_type(4)));

#define B_   8
#define DIM_ 64
#define HID_ 128
#define HW_  192
#define PW_  194            // padded width/height of xT

__device__ __forceinline__ void gl_lds16(const void* g, void* l) {
  __builtin_amdgcn_global_load_lds((__attribute__((address_space(1))) void*)(g),
                                   (__attribute__((address_space(3))) void*)(l),
                                   16, 0, 0);
}

// ws layout (bytes)
#define WS_XT    0u            // 8*194*194*64*2 = 38,539,264
#define WS_XSUM  38539264u     // 512 f32
#define WS_KARR  38541312u     // 8 * 9*128 f32 = 36,864
#define WS_WIA   38578176u     // 8192 bf16 = 16,384
#define WS_WOB   38594560u     // 16384 bf16 = 32,768

// ---------------------------------------------------------------------------
// prepw: w_in -> A-frag order [cc][kk][q][m][j] (o=16cc+m, c=32kk+8q+j)
//        w_out -> B-frag order [cc][q][j64][slot8] (slot<4: w_out[j][16cc+4q+slot], else 0)
// 24576 threads: 8192 for wiA, 16384 for woB.
// ---------------------------------------------------------------------------
__global__ __launch_bounds__(256) void dt_prepw(const float* __restrict__ w_in,
                                                const float* __restrict__ w_out,
                                                bf16* __restrict__ wiA,
                                                bf16* __restrict__ woB) {
  int i = blockIdx.x * 256 + threadIdx.x;          // 0..24575
  if (i < 8192) {
    int j = i & 7, m = (i >> 3) & 15, q = (i >> 7) & 3, kk = (i >> 9) & 1, cc = i >> 10;
    int o = cc * 16 + m, c = kk * 32 + q * 8 + j;
    wiA[i] = (bf16)w_in[o * DIM_ + c];
  } else {
    int i2 = i - 8192;                             // 0..16383
    int sl = i2 & 7, j = (i2 >> 3) & 63, q = (i2 >> 9) & 3, cc = i2 >> 11;  // cc 0..7
    float v = (sl < 4) ? w_out[j * HID_ + cc * 16 + q * 4 + sl] : 0.f;
    woB[i2] = (bf16)v;
  }
}

// ---------------------------------------------------------------------------
// prepx: one block per (b, padded row yy). Interior rows: transpose 64x192
// f32 -> 192 px * 64c bf16 (via LDS), plus channel partial sums -> atomicAdd.
// Border rows / cols written as zeros.
// ---------------------------------------------------------------------------
__global__ __launch_bounds__(256) void dt_prepx(const float* __restrict__ x,
                                                bf16* __restrict__ xT,
                                                float* __restrict__ xsum) {
  const int yy = blockIdx.x, b = blockIdx.y, t = threadIdx.x;
  bf16* xtrow = xT + ((size_t)(b * PW_ + yy)) * PW_ * DIM_;
  const bf16x8 z8 = {(bf16)0.f,(bf16)0.f,(bf16)0.f,(bf16)0.f,
                     (bf16)0.f,(bf16)0.f,(bf16)0.f,(bf16)0.f};
  if (yy == 0 || yy == PW_ - 1) {
    if (t < PW_) {
      bf16* dst = xtrow + t * DIM_;
#pragma unroll
      for (int c8 = 0; c8 < 8; ++c8) *(bf16x8*)(dst + c8 * 8) = z8;
    }
    return;
  }
  const int y = yy - 1;
  __shared__ float xr[DIM_ * HW_];                 // [c][px]
  const int c = t >> 2, qu = t & 3;
  const float4* rp = (const float4*)(x + ((size_t)(b * DIM_ + c) * HW_ + y) * HW_) + qu * 12;
  float s = 0.f;
#pragma unroll
  for (int i = 0; i < 12; ++i) {
    float4 v = rp[i];
    s += (v.x + v.y) + (v.z + v.w);
    ((float4*)xr)[c * 48 + qu * 12 + i] = v;
  }
  s += __shfl_down(s, 2);
  s += __shfl_down(s, 1);
  if ((t & 3) == 0) atomicAdd(xsum + b * DIM_ + c, s);
  __syncthreads();
  if (t < HW_) {
    const int px = t;
    bf16* dst = xtrow + (px + 1) * DIM_;
#pragma unroll
    for (int c8 = 0; c8 < 8; ++c8) {
      bf16x8 pk;
#pragma unroll
      for (int j2 = 0; j2 < 8; ++j2) pk[j2] = (bf16)xr[(c8 * 8 + j2) * HW_ + px];
      *(bf16x8*)(dst + c8 * 8) = pk;
    }
  } else if (t == HW_ || t == HW_ + 1) {           // border cols xx=0, xx=193
    bf16* dst = xtrow + (size_t)(t - HW_) * (PW_ - 1) * DIM_;
#pragma unroll
    for (int c8 = 0; c8 < 8; ++c8) *(bf16x8*)(dst + c8 * 8) = z8;
  }
}

// ---------------------------------------------------------------------------
// kgen: exact fp32. karr[b][tap][o], tap-major so kmain reads f32x4 over o.
// ---------------------------------------------------------------------------
__global__ __launch_bounds__(128) void dt_kgen(
    const float* __restrict__ xsum, const float* __restrict__ w_in,
    const float* __restrict__ b_in, const float* __restrict__ wg1,
    const float* __restrict__ bg1, const float* __restrict__ wg2,
    const float* __restrict__ bg2, float* __restrict__ karr) {
  const int b = blockIdx.x, t = threadIdx.x;
  __shared__ float xm[DIM_], hm[HID_], g[HID_];
  if (t < DIM_) xm[t] = xsum[b * DIM_ + t] * (1.f / (HW_ * HW_));
  __syncthreads();
  {
    float a = b_in[t];
    const float* w = w_in + t * DIM_;
    for (int c = 0; c < DIM_; ++c) a += w[c] * xm[c];
    hm[t] = a;
  }
  __syncthreads();
  {
    float a = bg1[t];
    const float* w = wg1 + t * HID_;
    for (int c = 0; c < HID_; ++c) a += w[c] * hm[c];
    g[t] = a > 0.f ? a : 0.f;
  }
  __syncthreads();
  for (int tp = 0; tp < 9; ++tp) {
    float s = bg2[t * 9 + tp];
    const float* w2 = wg2 + (size_t)(t * 9 + tp) * HID_;
    for (int c = 0; c < HID_; ++c) s += w2[c] * g[c];
    karr[b * 1152 + tp * HID_ + t] = s;
  }
}

// ---------------------------------------------------------------------------
// kmain. Grid (12,12,8), 256 threads (4 waves). Wave wv owns out rows
// 4wv..4wv+3 of the tile (h tile rows 4wv..4wv+5).
// LDS: [0,41472) x_s: 18 rows x (kk2 x q4 x px18) 16B chunks
//      [41472,46080) karr f32 [tap][128]
//      store bounce aliases [0,34048) after compute barrier.
// __launch_bounds__(256,2): 256-reg unified budget (2 blocks/CU). Peak
// arch live ~90 (h 12 + y 12 + taps 12 + wa 8 + wb 16 + bin 4 + masks 3 +
// x transients + addr) + acc3 64 AGPR -> no scratch spill.
// ---------------------------------------------------------------------------
#define XROWB 2304
#define KOFF  41472

// h-row macro: proj_in MFMAs for the 3 shifted column windows of smem row
// (wv*4+RR), plus wave-uniform-row masked bias add. Declares HL/HM/HR.
#define HROW(RR, HL, HM, HR)                                                  \
  f32x4 HL, HM, HR;                                                           \
  do {                                                                        \
    const char* rbase_ = smem + (wv * 4 + (RR)) * XROWB + q * 288 + m * 16;   \
    const f32x4 z_ = 0.f;                                                     \
    bf16x8 xa_ = *(const bf16x8*)(rbase_);                                    \
    bf16x8 xb_ = *(const bf16x8*)(rbase_ + 1152);                             \
    HL = __builtin_amdgcn_mfma_f32_16x16x32_bf16(wa0, xa_, z_, 0, 0, 0);      \
    HL = __builtin_amdgcn_mfma_f32_16x16x32_bf16(wa1, xb_, HL, 0, 0, 0);      \
    xa_ = *(const bf16x8*)(rbase_ + 16);                                      \
    xb_ = *(const bf16x8*)(rbase_ + 1152 + 16);                               \
    HM = __builtin_amdgcn_mfma_f32_16x16x32_bf16(wa0, xa_, z_, 0, 0, 0);      \
    HM = __builtin_amdgcn_mfma_f32_16x16x32_bf16(wa1, xb_, HM, 0, 0, 0);      \
    xa_ = *(const bf16x8*)(rbase_ + 32);                                      \
    xb_ = *(const bf16x8*)(rbase_ + 1152 + 32);                               \
    HR = __builtin_amdgcn_mfma_f32_16x16x32_bf16(wa0, xa_, z_, 0, 0, 0);      \
    HR = __builtin_amdgcn_mfma_f32_16x16x32_bf16(wa1, xb_, HR, 0, 0, 0);      \
    if ((unsigned)(rowg0 + wv * 4 + (RR)) < (unsigned)HW_) {                  \
      HL += bin4 * mL; HM += bin4 * mM; HR += bin4 * mR;                      \
    }                                                                         \
  } while (0)

// read one 3-tap row (dy = T/3) of the dynamic kernel from LDS (broadcast)
#define TAPROW(T, K0, K1, K2)                                                 \
  const f32x4 K0 = *(const f32x4*)(kvp + (T) * HID_);                         \
  const f32x4 K1 = *(const f32x4*)(kvp + ((T) + 1) * HID_);                   \
  const f32x4 K2 = *(const f32x4*)(kvp + ((T) + 2) * HID_)

#define CINIT(Y, HL, HM, HR)                                                  \
  do { TAPROW(0, k0_, k1_, k2_);                                              \
       Y = k0_ * HL + k1_ * HM + k2_ * HR; } while (0)

#define CMID(Y, HL, HM, HR)                                                   \
  do { TAPROW(3, k3_, k4_, k5_);                                              \
       Y += k3_ * HL; Y += k4_ * HM; Y += k5_ * HR; } while (0)

#define CEMIT(PY, Y, HL, HM, HR)                                              \
  do { TAPROW(6, k6_, k7_, k8_);                                              \
       f32x4 v_ = Y + k6_ * HL + k7_ * HM + k8_ * HR;                         \
       float a0_ = v_[0], a1_ = v_[1], a2_ = v_[2], a3_ = v_[3];              \
       bf16x8 af_ = {(bf16)fmaxf(a0_, 0.1f * a0_),                            \
                     (bf16)fmaxf(a1_, 0.1f * a1_),                            \
                     (bf16)fmaxf(a2_, 0.1f * a2_),                            \
                     (bf16)fmaxf(a3_, 0.1f * a3_),                            \
                     (bf16)0.f, (bf16)0.f, (bf16)0.f, (bf16)0.f};             \
       acc3[PY][0] = __builtin_amdgcn_mfma_f32_16x16x32_bf16(af_, wb0, acc3[PY][0], 0, 0, 0); \
       acc3[PY][1] = __builtin_amdgcn_mfma_f32_16x16x32_bf16(af_, wb1, acc3[PY][1], 0, 0, 0); \
       acc3[PY][2] = __builtin_amdgcn_mfma_f32_16x16x32_bf16(af_, wb2, acc3[PY][2], 0, 0, 0); \
       acc3[PY][3] = __builtin_amdgcn_mfma_f32_16x16x32_bf16(af_, wb3, acc3[PY][3], 0, 0, 0); \
  } while (0)

__global__ __launch_bounds__(256, 2) void dt_kmain(
    const bf16* __restrict__ xT, const bf16* __restrict__ wiA,
    const bf16* __restrict__ woB, const float* __restrict__ karr,
    const float* __restrict__ b_in, const float* __restrict__ b_out,
    float* __restrict__ out) {
  __shared__ __attribute__((aligned(16))) char smem[46080];
  const int t = threadIdx.x;
  const int wv = t >> 6, lane = t & 63;
  const int q = lane >> 4, m = lane & 15;
  const int tx = blockIdx.x, ty = blockIdx.y, b = blockIdx.z;

  // ---- stage x tile + karr via global_load_lds ---------------------------
  {
    const char* xbase = (const char*)xT +
        ((size_t)(b * PW_ + ty * 16) * PW_ + tx * 16) * (DIM_ * 2);
    for (int rr = wv; rr < 18; rr += 4) {
      const char* grow = xbase + (size_t)rr * (PW_ * DIM_ * 2);
      char* lrow = smem + rr * XROWB;
#pragma unroll
      for (int p = 0; p < 3; ++p) {
        int idx = p * 64 + lane;
        if (idx < 144) {
          int kq = (idx * 57) >> 10;        // idx / 18
          int px = idx - kq * 18;
          int goff = px * 128 + (kq >> 2) * 64 + (kq & 3) * 16;
          gl_lds16(grow + goff, lrow + p * 1024);
        }
      }
    }
    const char* kg = (const char*)karr + b * 4608;
    gl_lds16(kg + (wv * 64 + lane) * 16, smem + KOFF + wv * 1024);
    if (wv == 0 && lane < 32)
      gl_lds16(kg + (256 + lane) * 16, smem + KOFF + 4096);
  }
  __syncthreads();

  const int rowg0 = ty * 16 - 1;
  const int colg0 = tx * 16 - 1;
  const float mL = ((unsigned)(colg0 + 0 + m) < (unsigned)HW_) ? 1.f : 0.f;
  const float mM = ((unsigned)(colg0 + 1 + m) < (unsigned)HW_) ? 1.f : 0.f;
  const float mR = ((unsigned)(colg0 + 2 + m) < (unsigned)HW_) ? 1.f : 0.f;

  f32x4 acc3[4][4];
#pragma unroll
  for (int a = 0; a < 4; ++a)
#pragma unroll
    for (int n = 0; n < 4; ++n) acc3[a][n] = 0.f;

  const float* karrL = (const float*)(smem + KOFF);

  for (int cc = 0; cc < 8; ++cc) {
    const bf16x8 wa0 = *(const bf16x8*)((const char*)wiA + ((cc * 2 + 0) * 4 + q) * 256 + m * 16);
    const bf16x8 wa1 = *(const bf16x8*)((const char*)wiA + ((cc * 2 + 1) * 4 + q) * 256 + m * 16);
    const bf16x8 wb0 = *(const bf16x8*)((const char*)woB + (((cc * 4 + q) * 64) + 0 * 16 + m) * 16);
    const bf16x8 wb1 = *(const bf16x8*)((const char*)woB + (((cc * 4 + q) * 64) + 1 * 16 + m) * 16);
    const bf16x8 wb2 = *(const bf16x8*)((const char*)woB + (((cc * 4 + q) * 64) + 2 * 16 + m) * 16);
    const bf16x8 wb3 = *(const bf16x8*)((const char*)woB + (((cc * 4 + q) * 64) + 3 * 16 + m) * 16);
    const f32x4 bin4 = *(const f32x4*)(b_in + cc * 16 + q * 4);
    const float* kvp = karrL + cc * 16 + q * 4;   // tap tp lives at kvp+tp*128

    // Hand-unrolled 6-row stream: h row rr feeds outputs py=rr-2..rr as
    // tap-row dy=rr-py. All indices literal; y0..y3 are named registers.
    f32x4 y0, y1, y2, y3;
    HROW(0, hL0, hM0, hR0);
    CINIT(y0, hL0, hM0, hR0);
    HROW(1, hL1, hM1, hR1);
    CMID (y0, hL1, hM1, hR1);
    CINIT(y1, hL1, hM1, hR1);
    HROW(2, hL2, hM2, hR2);
    CEMIT(0, y0, hL2, hM2, hR2);
    CMID (y1, hL2, hM2, hR2);
    CINIT(y2, hL2, hM2, hR2);
    HROW(3, hL3, hM3, hR3);
    CEMIT(1, y1, hL3, hM3, hR3);
    CMID (y2, hL3, hM3, hR3);
    CINIT(y3, hL3, hM3, hR3);
    HROW(4, hL4, hM4, hR4);
    CEMIT(2, y2, hL4, hM4, hR4);
    CMID (y3, hL4, hM4, hR4);
    HROW(5, hL5, hM5, hR5);
    CEMIT(3, y3, hL5, hM5, hR5);
  }
  __syncthreads();          // x_s / karr dead; bounce region reuses smem

  // ---- store via LDS bounce: aligned 64B f32x4 rows ----------------------
  float* smemF = (float*)smem;                      // [j][132] f32, halves of 8 rows
  const int c4 = t & 3, js = (t >> 2) & 63;
  const float bo = b_out[js];
  float* obase = out + ((size_t)(b * DIM_ + js) * HW_ + (ty * 16)) * HW_ + tx * 16 + c4 * 4;
#pragma unroll
  for (int half = 0; half < 2; ++half) {
    if ((wv >> 1) == half) {
#pragma unroll
      for (int py = 0; py < 4; ++py) {
        const int lrow = (wv * 4 + py) & 7;
#pragma unroll
        for (int nt = 0; nt < 4; ++nt)
          *(f32x4*)(smemF + (nt * 16 + m) * 132 + lrow * 16 + q * 4) = acc3[py][nt];
      }
    }
    __syncthreads();
#pragma unroll
    for (int lrow = 0; lrow < 8; ++lrow) {
      f32x4 v = *(const f32x4*)(smemF + js * 132 + lrow * 16 + c4 * 4);
      v += bo;
      *(f32x4*)(obase + (size_t)(half * 8 + lrow) * HW_) = v;
    }
    __syncthreads();
  }
}

// ---------------------------------------------------------------------------
extern "C" void kernel_launch(void* const* d_in, const int* in_sizes, int n_in,
                              void* d_out, int out_size, void* d_ws,
                              size_t ws_size, hipStream_t stream) {
  const float* x     = (const float*)d_in[0];
  const float* w_in  = (const float*)d_in[1];
  const float* b_in  = (const float*)d_in[2];
  const float* wg1   = (const float*)d_in[3];
  const float* bg1   = (const float*)d_in[4];
  const float* wg2   = (const float*)d_in[5];
  const float* bg2   = (const float*)d_in[6];
  const float* w_out = (const float*)d_in[7];
  const float* b_out = (const float*)d_in[8];
  float* out = (float*)d_out;

  char* ws = (char*)d_ws;
  bf16*  xT   = (bf16*)(ws + WS_XT);
  float* xsum = (float*)(ws + WS_XSUM);
  float* karr = (float*)(ws + WS_KARR);
  bf16*  wiA  = (bf16*)(ws + WS_WIA);
  bf16*  woB  = (bf16*)(ws + WS_WOB);

  hipMemsetAsync(xsum, 0, B_ * DIM_ * sizeof(float), stream);
  dt_prepw<<<dim3(96), dim3(256), 0, stream>>>(w_in, w_out, wiA, woB);
  dt_prepx<<<dim3(PW_, B_), dim3(256), 0, stream>>>(x, xT, xsum);
  dt_kgen<<<dim3(B_), dim3(128), 0, stream>>>(xsum, w_in, b_in, wg1, bg1, wg2,
                                              bg2, karr);
  dt_kmain<<<dim3(12, 12, B_), dim3(256), 0, stream>>>(xT, wiA, woB, karr,
                                                       b_in, b_out, out);
}